// Round 5
// baseline (417.716 us; speedup 1.0000x reference)
//
#include <hip/hip_runtime.h>

constexpr int NN   = 50000;
constexpr int PADN = 50048;       // 391*128, padded rows
constexpr int KD   = 128;
constexpr int RR   = 8;
constexpr int NSEG = RR * NN;     // 400000
constexpr int NBLK = 196;         // scan blocks: 196*2048 = 401408 >= NSEG
constexpr int PADSEG = NBLK * 2048;

typedef __attribute__((ext_vector_type(8))) short short8;
typedef __attribute__((ext_vector_type(4))) float f32x4;

__device__ __forceinline__ float bflo(unsigned u){ return __uint_as_float(u << 16); }
__device__ __forceinline__ float bfhi(unsigned u){ return __uint_as_float(u & 0xffff0000u); }
__device__ __forceinline__ unsigned pk_bf16(float a, float b){
  unsigned ua = __float_as_uint(a), ub = __float_as_uint(b);
  ua = (ua + 0x7fffu + ((ua >> 16) & 1u)) >> 16;
  ub = (ub + 0x7fffu + ((ub >> 16) & 1u)) & 0xffff0000u;
  return (ua & 0xffffu) | ub;
}
__device__ __forceinline__ unsigned short bf1(float a){
  unsigned ua = __float_as_uint(a);
  return (unsigned short)((ua + 0x7fffu + ((ua >> 16) & 1u)) >> 16);
}

// ---------------- structure build ----------------
__global__ __launch_bounds__(256)
void count_edges(const int* __restrict__ dst, const int* __restrict__ et,
                 int E, int* __restrict__ cnt) {
  const int e = blockIdx.x * 256 + threadIdx.x;
  if (e < E) atomicAdd(&cnt[et[e] * NN + dst[e]], 1);
}

// hierarchical exclusive scan, stage 1: per-block (2048 segs) scan, no atomics
__global__ __launch_bounds__(256)
void scan_block(const int* __restrict__ cnt, int* __restrict__ fillpos,
                int* __restrict__ blkSum) {
  const int t = threadIdx.x;
  const int base = blockIdx.x * 2048 + t * 8;
  const int4 a = *(const int4*)&cnt[base];
  const int4 b = *(const int4*)&cnt[base + 4];
  const int s8[8] = {a.x, a.y, a.z, a.w, b.x, b.y, b.z, b.w};
  int tsum = 0;
#pragma unroll
  for (int i = 0; i < 8; ++i) tsum += s8[i];
  int inc = tsum;
#pragma unroll
  for (int o = 1; o < 64; o <<= 1) {
    int v = __shfl_up(inc, o);
    if ((t & 63) >= o) inc += v;
  }
  __shared__ int wsum[4];
  if ((t & 63) == 63) wsum[t >> 6] = inc;
  __syncthreads();
  int wpre = 0;
#pragma unroll
  for (int w = 0; w < 4; ++w) if (w < (t >> 6)) wpre += wsum[w];
  int run = wpre + inc - tsum;
  int o8[8];
#pragma unroll
  for (int i = 0; i < 8; ++i) { o8[i] = run; run += s8[i]; }
  *(int4*)&fillpos[base]     = make_int4(o8[0], o8[1], o8[2], o8[3]);
  *(int4*)&fillpos[base + 4] = make_int4(o8[4], o8[5], o8[6], o8[7]);
  if (t == 255) blkSum[blockIdx.x] = wpre + inc;
}

__global__ __launch_bounds__(256)
void scan_tops(int* __restrict__ blkSum) {
  const int t = threadIdx.x;
  const int v = (t < NBLK) ? blkSum[t] : 0;
  int inc = v;
#pragma unroll
  for (int o = 1; o < 64; o <<= 1) {
    int u = __shfl_up(inc, o);
    if ((t & 63) >= o) inc += u;
  }
  __shared__ int wsum[4];
  if ((t & 63) == 63) wsum[t >> 6] = inc;
  __syncthreads();
  int wpre = 0;
#pragma unroll
  for (int w = 0; w < 4; ++w) if (w < (t >> 6)) wpre += wsum[w];
  if (t < NBLK) blkSum[t] = wpre + inc - v;
}

__global__ __launch_bounds__(256)
void scan_apply(int* __restrict__ fillpos, const int* __restrict__ blkSum) {
  const int base = blockIdx.x * 2048 + threadIdx.x * 8;
  const int off = blkSum[blockIdx.x];
  int4 a = *(int4*)&fillpos[base];
  int4 b = *(int4*)&fillpos[base + 4];
  a.x += off; a.y += off; a.z += off; a.w += off;
  b.x += off; b.y += off; b.z += off; b.w += off;
  *(int4*)&fillpos[base]     = a;
  *(int4*)&fillpos[base + 4] = b;
}

__global__ __launch_bounds__(256)
void fill_edges(const int* __restrict__ src, const int* __restrict__ dst,
                const int* __restrict__ et, int E,
                int* __restrict__ fillpos, int* __restrict__ srt) {
  const int e = blockIdx.x * 256 + threadIdx.x;
  if (e < E) {
    const int seg = et[e] * NN + dst[e];
    srt[atomicAdd(&fillpos[seg], 1)] = src[e];
  }
}

// ---------------- conversions ----------------
__global__ __launch_bounds__(256)
void convert_x(const float* __restrict__ x, unsigned* __restrict__ xb) {
  const int idx = blockIdx.x * 256 + threadIdx.x;   // one per 8 elems
  if (idx >= PADN * 16) return;
  const int row = idx >> 4, o = (idx & 15) * 8;
  uint4 v = make_uint4(0u, 0u, 0u, 0u);
  if (row < NN) {
    float4 a = *(const float4*)&x[(size_t)row * KD + o];
    float4 b = *(const float4*)&x[(size_t)row * KD + o + 4];
    v.x = pk_bf16(a.x, a.y); v.y = pk_bf16(a.z, a.w);
    v.z = pk_bf16(b.x, b.y); v.w = pk_bf16(b.z, b.w);
  }
  *(uint4*)&xb[(size_t)idx * 4] = v;
}

// Wt[9][Nw][128] bf16  <-  W[8][128][Nw] fp32 (transposed), ch 8 = root[128][Nw]
__global__ __launch_bounds__(256)
void prep_w(const float* __restrict__ W, const float* __restrict__ root,
            unsigned short* __restrict__ Wt, int Nw) {
  const int idx = blockIdx.x * 256 + threadIdx.x;
  if (idx >= 9 * Nw * KD) return;
  const int k = idx & 127;
  const int n = (idx >> 7) % Nw;
  const int ch = idx / (Nw * KD);
  const float v = (ch < 8) ? W[((size_t)ch * KD + k) * Nw + n] : root[(size_t)k * Nw + n];
  Wt[idx] = bf1(v);
}

// ---------------- fused gather + MFMA GEMM ----------------
// C[M,BN] = sum_{ch<8} mean_ch(X)[M,128] @ Wt_ch^T + X[M,128] @ Wt_8^T (+bias)(relu)
// BM=128, full K=128 per chunk, 256 threads = 4 waves.
// LDS rows 256B (16 x 16B slots), XOR-swizzle slot ^= (row & 15).
template<int BN, bool RELU, bool OUTBF16>
__global__ __launch_bounds__(256)
void rgcn_fused(const unsigned* __restrict__ Xb,          // [PADN][64] uint (bf16x2)
                const unsigned short* __restrict__ Wt,    // [9][BN][128] bf16
                const float* __restrict__ bias,
                const int* __restrict__ srt,
                const int* __restrict__ segend,
                const int* __restrict__ cnt,
                void* __restrict__ Cout) {
  constexpr int WM = (BN == 128) ? 64 : 32;
  constexpr int MF = WM / 16;
  constexpr int NF = 4;
  constexpr int WAVES_N = BN / 64;

  __shared__ uint4 ldsv[(128 * 256 + BN * 256) / 16];
  char* As = (char*)ldsv;                  // [128][256B] swizzled
  char* Bs = (char*)ldsv + 128 * 256;      // [BN][256B]  swizzled

  const int t = threadIdx.x;
  const int l = t & 63;
  const int w = t >> 6;
  const int wr = w / WAVES_N;
  const int wc = w % WAVES_N;
  const int row0 = blockIdx.x * 128;
  const int l15 = l & 15, lq = l >> 4;
  const int grp = t >> 4, lane = t & 15;

  f32x4 acc[MF][NF];
#pragma unroll
  for (int mi = 0; mi < MF; ++mi)
#pragma unroll
    for (int ni = 0; ni < NF; ++ni) acc[mi][ni] = (f32x4){0.f, 0.f, 0.f, 0.f};

  for (int ch = 0; ch < 9; ++ch) {
    __syncthreads();   // protect previous chunk's LDS reads
    // ---- stage B: Wt[ch] (BN rows x 128 k) ----
    {
      const unsigned short* bP = Wt + (size_t)ch * BN * KD;
#pragma unroll
      for (int i = 0; i < BN / 16; ++i) {
        const int s = t + i * 256;
        const int r = s >> 4, c16 = s & 15;
        uint4 v = *(const uint4*)(bP + (size_t)r * KD + c16 * 8);
        *(uint4*)(Bs + r * 256 + ((c16 ^ (r & 15)) * 16)) = v;
      }
    }
    // ---- stage A ----
    if (ch < 8) {
      // gathered mean rows: 16 lanes per segment, 8 passes of 16 segments
      const int* cP = cnt + (size_t)ch * NN;
      const int* eP = segend + (size_t)ch * NN;
#pragma unroll
      for (int p = 0; p < 8; ++p) {
        const int dr = p * 16 + grp;
        const int d = row0 + dr;
        int c = 0, base = 0;
        if (d < NN) { c = cP[d]; base = eP[d] - c; }
        float a0=0,a1=0,a2=0,a3=0,a4=0,a5=0,a6=0,a7=0;
        int i = 0;
        for (; i + 1 < c; i += 2) {          // 2-edge unroll for MLP
          const int s0 = srt[base + i], s1 = srt[base + i + 1];
          const uint4 v0 = *(const uint4*)&Xb[(size_t)s0 * 64 + lane * 4];
          const uint4 v1 = *(const uint4*)&Xb[(size_t)s1 * 64 + lane * 4];
          a0 += bflo(v0.x) + bflo(v1.x); a1 += bfhi(v0.x) + bfhi(v1.x);
          a2 += bflo(v0.y) + bflo(v1.y); a3 += bfhi(v0.y) + bfhi(v1.y);
          a4 += bflo(v0.z) + bflo(v1.z); a5 += bfhi(v0.z) + bfhi(v1.z);
          a6 += bflo(v0.w) + bflo(v1.w); a7 += bfhi(v0.w) + bfhi(v1.w);
        }
        if (i < c) {
          const uint4 v0 = *(const uint4*)&Xb[(size_t)srt[base + i] * 64 + lane * 4];
          a0 += bflo(v0.x); a1 += bfhi(v0.x);
          a2 += bflo(v0.y); a3 += bfhi(v0.y);
          a4 += bflo(v0.z); a5 += bfhi(v0.z);
          a6 += bflo(v0.w); a7 += bfhi(v0.w);
        }
        const float sc = (c > 0) ? 1.0f / (float)c : 0.0f;
        uint4 o;
        o.x = pk_bf16(a0 * sc, a1 * sc); o.y = pk_bf16(a2 * sc, a3 * sc);
        o.z = pk_bf16(a4 * sc, a5 * sc); o.w = pk_bf16(a6 * sc, a7 * sc);
        *(uint4*)(As + dr * 256 + ((lane ^ (dr & 15)) * 16)) = o;
      }
    } else {
      // root chunk: direct rows of Xb
#pragma unroll
      for (int i = 0; i < 8; ++i) {
        const int s = t + i * 256;
        const int r = s >> 4, c16 = s & 15;
        uint4 v = *(const uint4*)&Xb[(size_t)(row0 + r) * 64 + c16 * 4];
        *(uint4*)(As + r * 256 + ((c16 ^ (r & 15)) * 16)) = v;
      }
    }
    __syncthreads();
    // ---- MFMA over K=128 (4 x 32) ----
#pragma unroll
    for (int ks = 0; ks < 4; ++ks) {
      short8 bfr[NF];
#pragma unroll
      for (int ni = 0; ni < NF; ++ni) {
        const int br = wc * 64 + ni * 16 + l15;
        bfr[ni] = *(const short8*)(Bs + br * 256 + (((ks * 4 + lq) ^ (br & 15)) * 16));
      }
#pragma unroll
      for (int mi = 0; mi < MF; ++mi) {
        const int ar = wr * WM + mi * 16 + l15;
        const short8 af = *(const short8*)(As + ar * 256 + (((ks * 4 + lq) ^ (ar & 15)) * 16));
#pragma unroll
        for (int ni = 0; ni < NF; ++ni)
          acc[mi][ni] = __builtin_amdgcn_mfma_f32_16x16x32_bf16(af, bfr[ni], acc[mi][ni], 0, 0, 0);
      }
    }
  }

  // ---- epilogue ----
#pragma unroll
  for (int ni = 0; ni < NF; ++ni) {
    const int col = wc * 64 + ni * 16 + l15;
    const float bv = bias[col];
#pragma unroll
    for (int mi = 0; mi < MF; ++mi) {
#pragma unroll
      for (int q = 0; q < 4; ++q) {
        const int grow = row0 + wr * WM + mi * 16 + lq * 4 + q;
        if (grow < NN) {
          float v = acc[mi][ni][q] + bv;
          if (RELU) v = fmaxf(v, 0.f);
          if (OUTBF16) ((unsigned short*)Cout)[(size_t)grow * BN + col] = bf1(v);
          else         ((float*)Cout)[(size_t)grow * BN + col] = v;
        } else if (OUTBF16) {
          ((unsigned short*)Cout)[(size_t)grow * BN + col] = 0;  // clean pad rows
        }
      }
    }
  }
}

// ---------------- launch ----------------
extern "C" void kernel_launch(void* const* d_in, const int* in_sizes, int n_in,
                              void* d_out, int out_size, void* d_ws, size_t ws_size,
                              hipStream_t stream) {
  const float* x     = (const float*)d_in[0];
  const int*   ei    = (const int*)d_in[1];
  const int*   et    = (const int*)d_in[2];
  const float* W1    = (const float*)d_in[3];
  const float* root1 = (const float*)d_in[4];
  const float* b1    = (const float*)d_in[5];
  const float* W2    = (const float*)d_in[6];
  const float* root2 = (const float*)d_in[7];
  const float* b2    = (const float*)d_in[8];
  float* out = (float*)d_out;

  const int E = in_sizes[2];
  const int* src  = ei;
  const int* dstv = ei + E;

  // workspace layout (~32.5 MB, 16B-aligned)
  char* ws = (char*)d_ws;
  unsigned short* xb  = (unsigned short*)ws;                 // 12,812,288 B
  unsigned short* hb  = (unsigned short*)(ws + 12812288);    // 12,812,288 B
  unsigned short* Wt1 = (unsigned short*)(ws + 25624576);    //    294,912 B
  unsigned short* Wt2 = (unsigned short*)(ws + 25919488);    //    147,456 B
  int* cnt     = (int*)(ws + 26066944);                      //  1,605,632 B
  int* fillpos = (int*)(ws + 27672576);                      //  1,605,632 B
  int* blkSum  = (int*)(ws + 29278208);                      //      1,024 B
  int* srt     = (int*)(ws + 29279232);                      //  3,200,000 B

  // build segment structure: count -> scan (no global atomics) -> fill
  hipMemsetAsync(cnt, 0, sizeof(int) * (size_t)PADSEG, stream);
  count_edges<<<(E + 255) / 256, 256, 0, stream>>>(dstv, et, E, cnt);
  scan_block<<<NBLK, 256, 0, stream>>>(cnt, fillpos, blkSum);
  scan_tops<<<1, 256, 0, stream>>>(blkSum);
  scan_apply<<<NBLK, 256, 0, stream>>>(fillpos, blkSum);
  fill_edges<<<(E + 255) / 256, 256, 0, stream>>>(src, dstv, et, E, fillpos, srt);
  // after fill: fillpos[s] = segment end

  convert_x<<<PADN * 16 / 256, 256, 0, stream>>>(x, (unsigned*)xb);
  prep_w<<<(9 * 128 * KD + 255) / 256, 256, 0, stream>>>(W1, root1, Wt1, 128);
  prep_w<<<(9 * 64 * KD + 255) / 256, 256, 0, stream>>>(W2, root2, Wt2, 64);

  const int mBlocks = PADN / 128;       // 391

  // layer 1: h = relu(...)   (fused gather + GEMM, bf16 out)
  rgcn_fused<128, true, true><<<mBlocks, 256, 0, stream>>>(
      (const unsigned*)xb, Wt1, b1, srt, fillpos, cnt, hb);

  // layer 2: out = ...       (fused gather + GEMM, fp32 out)
  rgcn_fused<64, false, false><<<mBlocks, 256, 0, stream>>>(
      (const unsigned*)hb, Wt2, b2, srt, fillpos, cnt, out);
}

// Round 6
// 257.277 us; speedup vs baseline: 1.6236x; 1.6236x over previous
//
#include <hip/hip_runtime.h>

constexpr int NN   = 50000;
constexpr int PADN = 50048;       // 391*128, padded rows
constexpr int KD   = 128;
constexpr int RR   = 8;
constexpr int NSEG = RR * NN;     // 400000
constexpr int NBLK = 196;         // scan blocks: 196*2048 = 401408 >= NSEG
constexpr int PADSEG = NBLK * 2048;

typedef __attribute__((ext_vector_type(8))) short short8;
typedef __attribute__((ext_vector_type(4))) float f32x4;
typedef __attribute__((ext_vector_type(4))) unsigned int u32x4;

__device__ __forceinline__ float bflo(unsigned u){ return __uint_as_float(u << 16); }
__device__ __forceinline__ float bfhi(unsigned u){ return __uint_as_float(u & 0xffff0000u); }
__device__ __forceinline__ unsigned pk_bf16(float a, float b){
  unsigned ua = __float_as_uint(a), ub = __float_as_uint(b);
  ua = (ua + 0x7fffu + ((ua >> 16) & 1u)) >> 16;
  ub = (ub + 0x7fffu + ((ub >> 16) & 1u)) & 0xffff0000u;
  return (ua & 0xffffu) | ub;
}
__device__ __forceinline__ unsigned short bf1(float a){
  unsigned ua = __float_as_uint(a);
  return (unsigned short)((ua + 0x7fffu + ((ua >> 16) & 1u)) >> 16);
}

// ---------------- fused convert_x + count_edges ----------------
__global__ __launch_bounds__(256)
void convert_count(const float* __restrict__ x, unsigned* __restrict__ xb,
                   const int* __restrict__ dst, const int* __restrict__ et,
                   int E, int* __restrict__ cnt) {
  const int idx = blockIdx.x * 256 + threadIdx.x;
  if (idx < E) atomicAdd(&cnt[et[idx] * NN + dst[idx]], 1);
  // convert: one thread per 8 floats
  if (idx < PADN * 16) {
    const int row = idx >> 4, o = (idx & 15) * 8;
    uint4 v = make_uint4(0u, 0u, 0u, 0u);
    if (row < NN) {
      float4 a = *(const float4*)&x[(size_t)row * KD + o];
      float4 b = *(const float4*)&x[(size_t)row * KD + o + 4];
      v.x = pk_bf16(a.x, a.y); v.y = pk_bf16(a.z, a.w);
      v.z = pk_bf16(b.x, b.y); v.w = pk_bf16(b.z, b.w);
    }
    *(uint4*)&xb[(size_t)idx * 4] = v;
  }
}

// hierarchical exclusive scan, stage 1: per-block (2048 segs) scan, no atomics
__global__ __launch_bounds__(256)
void scan_block(const int* __restrict__ cnt, int* __restrict__ fillpos,
                int* __restrict__ blkSum) {
  const int t = threadIdx.x;
  const int base = blockIdx.x * 2048 + t * 8;
  const int4 a = *(const int4*)&cnt[base];
  const int4 b = *(const int4*)&cnt[base + 4];
  const int s8[8] = {a.x, a.y, a.z, a.w, b.x, b.y, b.z, b.w};
  int tsum = 0;
#pragma unroll
  for (int i = 0; i < 8; ++i) tsum += s8[i];
  int inc = tsum;
#pragma unroll
  for (int o = 1; o < 64; o <<= 1) {
    int v = __shfl_up(inc, o);
    if ((t & 63) >= o) inc += v;
  }
  __shared__ int wsum[4];
  if ((t & 63) == 63) wsum[t >> 6] = inc;
  __syncthreads();
  int wpre = 0;
#pragma unroll
  for (int w = 0; w < 4; ++w) if (w < (t >> 6)) wpre += wsum[w];
  int run = wpre + inc - tsum;
  int o8[8];
#pragma unroll
  for (int i = 0; i < 8; ++i) { o8[i] = run; run += s8[i]; }
  *(int4*)&fillpos[base]     = make_int4(o8[0], o8[1], o8[2], o8[3]);
  *(int4*)&fillpos[base + 4] = make_int4(o8[4], o8[5], o8[6], o8[7]);
  if (t == 255) blkSum[blockIdx.x] = wpre + inc;
}

__global__ __launch_bounds__(256)
void scan_tops(int* __restrict__ blkSum) {
  const int t = threadIdx.x;
  const int v = (t < NBLK) ? blkSum[t] : 0;
  int inc = v;
#pragma unroll
  for (int o = 1; o < 64; o <<= 1) {
    int u = __shfl_up(inc, o);
    if ((t & 63) >= o) inc += u;
  }
  __shared__ int wsum[4];
  if ((t & 63) == 63) wsum[t >> 6] = inc;
  __syncthreads();
  int wpre = 0;
#pragma unroll
  for (int w = 0; w < 4; ++w) if (w < (t >> 6)) wpre += wsum[w];
  if (t < NBLK) blkSum[t] = wpre + inc - v;
}

__global__ __launch_bounds__(256)
void scan_apply(int* __restrict__ fillpos, const int* __restrict__ blkSum) {
  const int base = blockIdx.x * 2048 + threadIdx.x * 8;
  const int off = blkSum[blockIdx.x];
  int4 a = *(int4*)&fillpos[base];
  int4 b = *(int4*)&fillpos[base + 4];
  a.x += off; a.y += off; a.z += off; a.w += off;
  b.x += off; b.y += off; b.z += off; b.w += off;
  *(int4*)&fillpos[base]     = a;
  *(int4*)&fillpos[base + 4] = b;
}

__global__ __launch_bounds__(256)
void fill_edges(const int* __restrict__ src, const int* __restrict__ dst,
                const int* __restrict__ et, int E,
                int* __restrict__ fillpos, int* __restrict__ srt) {
  const int e = blockIdx.x * 256 + threadIdx.x;
  if (e < E) {
    const int seg = et[e] * NN + dst[e];
    srt[atomicAdd(&fillpos[seg], 1)] = src[e];
  }
}

// Wt1[9][128][128] and Wt2[9][64][128] bf16, transposed, in one dispatch
__global__ __launch_bounds__(256)
void prep_w(const float* __restrict__ W1, const float* __restrict__ root1,
            const float* __restrict__ W2, const float* __restrict__ root2,
            unsigned short* __restrict__ Wt1, unsigned short* __restrict__ Wt2) {
  int idx = blockIdx.x * 256 + threadIdx.x;
  if (idx < 9 * 128 * KD) {
    const int k = idx & 127;
    const int n = (idx >> 7) & 127;
    const int ch = idx >> 14;
    const float v = (ch < 8) ? W1[((size_t)ch * KD + k) * 128 + n] : root1[(size_t)k * 128 + n];
    Wt1[idx] = bf1(v);
  } else {
    idx -= 9 * 128 * KD;
    const int k = idx & 127;
    const int n = (idx >> 7) & 63;
    const int ch = idx >> 13;
    const float v = (ch < 8) ? W2[((size_t)ch * KD + k) * 64 + n] : root2[(size_t)k * 64 + n];
    Wt2[idx] = bf1(v);
  }
}

// ---------------- gather: agg[r][d][:] = mean of bf16 X rows ----------------
// 16 lanes per segment; NT store so the 100MB agg stream doesn't thrash L3
__global__ __launch_bounds__(256)
void gather_mean(const unsigned* __restrict__ Xb,         // [PADN][64] uint
                 const int* __restrict__ srt,
                 const int* __restrict__ segend, const int* __restrict__ cnt,
                 unsigned* __restrict__ agg) {            // [8][PADN][64] uint
  const int g = blockIdx.x * 16 + (threadIdx.x >> 4);
  const int lane = threadIdx.x & 15;
  const int c = cnt[g];
  const int base = segend[g] - c;
  float acc[8] = {};
  int i = 0;
  for (; i + 1 < c; i += 2) {
    const int s0 = srt[base + i], s1 = srt[base + i + 1];
    const uint4 v0 = *(const uint4*)&Xb[(size_t)s0 * 64 + lane * 4];
    const uint4 v1 = *(const uint4*)&Xb[(size_t)s1 * 64 + lane * 4];
    acc[0] += bflo(v0.x) + bflo(v1.x); acc[1] += bfhi(v0.x) + bfhi(v1.x);
    acc[2] += bflo(v0.y) + bflo(v1.y); acc[3] += bfhi(v0.y) + bfhi(v1.y);
    acc[4] += bflo(v0.z) + bflo(v1.z); acc[5] += bfhi(v0.z) + bfhi(v1.z);
    acc[6] += bflo(v0.w) + bflo(v1.w); acc[7] += bfhi(v0.w) + bfhi(v1.w);
  }
  if (i < c) {
    const uint4 v0 = *(const uint4*)&Xb[(size_t)srt[base + i] * 64 + lane * 4];
    acc[0] += bflo(v0.x); acc[1] += bfhi(v0.x);
    acc[2] += bflo(v0.y); acc[3] += bfhi(v0.y);
    acc[4] += bflo(v0.z); acc[5] += bfhi(v0.z);
    acc[6] += bflo(v0.w); acc[7] += bfhi(v0.w);
  }
  const float sc = (c > 0) ? 1.0f / (float)c : 0.0f;
  u32x4 o;
  o.x = pk_bf16(acc[0] * sc, acc[1] * sc); o.y = pk_bf16(acc[2] * sc, acc[3] * sc);
  o.z = pk_bf16(acc[4] * sc, acc[5] * sc); o.w = pk_bf16(acc[6] * sc, acc[7] * sc);
  const int r = g / NN, d = g - r * NN;
  __builtin_nontemporal_store(o, (u32x4*)&agg[((size_t)r * PADN + d) * 64 + lane * 4]);
}

// ---------------- MFMA GEMM ----------------
// C[M,BN] = sum_{ch<8} agg_ch[M,128] @ Wt_ch^T + xrow[M,128] @ Wt_8^T (+bias)(relu)
// BM=128, BK=64, 256 threads = 4 waves. LDS XOR-swizzled. A loads non-temporal
// (read-once stream; keep L3 for xb/hb/Wt).
template<int BN, bool RELU, bool OUTBF16>
__global__ __launch_bounds__(256)
void rgcn_gemm_mfma(const unsigned short* __restrict__ agg,   // [8][PADN][128] bf16
                    const unsigned short* __restrict__ xrow,  // [PADN][128] bf16
                    const unsigned short* __restrict__ Wt,    // [9][BN][128] bf16
                    const float* __restrict__ bias,
                    void* __restrict__ Cout) {
  constexpr int WM = (BN == 128) ? 64 : 32;
  constexpr int MF = WM / 16;
  constexpr int NF = 4;
  constexpr int WAVES_N = BN / 64;

  __shared__ uint4 ldsv[(128 * 128 + BN * 128) / 16];
  char* As = (char*)ldsv;                 // [128][128B] swizzled
  char* Bs = (char*)ldsv + 128 * 128;     // [BN][128B]  swizzled

  const int t = threadIdx.x;
  const int l = t & 63;
  const int w = t >> 6;
  const int wr = w / WAVES_N;
  const int wc = w % WAVES_N;
  const int row0 = blockIdx.x * 128;
  const int l15 = l & 15, lq = l >> 4;

  f32x4 acc[MF][NF];
#pragma unroll
  for (int mi = 0; mi < MF; ++mi)
#pragma unroll
    for (int ni = 0; ni < NF; ++ni) acc[mi][ni] = (f32x4){0.f, 0.f, 0.f, 0.f};

  for (int ch = 0; ch < 9; ++ch) {
    const unsigned short* aP = (ch < 8) ? (agg + (size_t)ch * PADN * KD) : xrow;
    const unsigned short* bP = Wt + (size_t)ch * BN * KD;
#pragma unroll
    for (int kt = 0; kt < 2; ++kt) {
      __syncthreads();
      // stage A: 128 rows x 64 bf16 (NT loads — streamed once)
#pragma unroll
      for (int i = 0; i < 4; ++i) {
        const int s = t + i * 256;
        const int r = s >> 3, c16 = s & 7;
        u32x4 v = __builtin_nontemporal_load(
            (const u32x4*)(aP + (size_t)(row0 + r) * KD + kt * 64 + c16 * 8));
        *(u32x4*)(As + r * 128 + ((c16 ^ (r & 7)) * 16)) = v;
      }
      // stage B: BN rows x 64 bf16
#pragma unroll
      for (int i = 0; i < BN / 32; ++i) {
        const int s = t + i * 256;
        const int r = s >> 3, c16 = s & 7;
        uint4 v = *(const uint4*)(bP + (size_t)r * KD + kt * 64 + c16 * 8);
        *(uint4*)(Bs + r * 128 + ((c16 ^ (r & 7)) * 16)) = v;
      }
      __syncthreads();
#pragma unroll
      for (int ks = 0; ks < 2; ++ks) {
        short8 bfr[NF];
#pragma unroll
        for (int ni = 0; ni < NF; ++ni) {
          const int br = wc * 64 + ni * 16 + l15;
          bfr[ni] = *(const short8*)(Bs + br * 128 + (((ks * 4 + lq) ^ (br & 7)) * 16));
        }
#pragma unroll
        for (int mi = 0; mi < MF; ++mi) {
          const int ar = wr * WM + mi * 16 + l15;
          short8 af = *(const short8*)(As + ar * 128 + (((ks * 4 + lq) ^ (ar & 7)) * 16));
#pragma unroll
          for (int ni = 0; ni < NF; ++ni)
            acc[mi][ni] = __builtin_amdgcn_mfma_f32_16x16x32_bf16(af, bfr[ni], acc[mi][ni], 0, 0, 0);
        }
      }
    }
  }
  // epilogue
#pragma unroll
  for (int ni = 0; ni < NF; ++ni) {
    const int col = wc * 64 + ni * 16 + l15;
    const float bv = bias[col];
#pragma unroll
    for (int mi = 0; mi < MF; ++mi) {
#pragma unroll
      for (int q = 0; q < 4; ++q) {
        const int grow = row0 + wr * WM + mi * 16 + lq * 4 + q;
        if (grow < NN) {
          float v = acc[mi][ni][q] + bv;
          if (RELU) v = fmaxf(v, 0.f);
          if (OUTBF16) ((unsigned short*)Cout)[(size_t)grow * BN + col] = bf1(v);
          else         ((float*)Cout)[(size_t)grow * BN + col] = v;
        } else if (OUTBF16) {
          ((unsigned short*)Cout)[(size_t)grow * BN + col] = 0;  // clean pad rows
        }
      }
    }
  }
}

// ---------------- launch ----------------
extern "C" void kernel_launch(void* const* d_in, const int* in_sizes, int n_in,
                              void* d_out, int out_size, void* d_ws, size_t ws_size,
                              hipStream_t stream) {
  const float* x     = (const float*)d_in[0];
  const int*   ei    = (const int*)d_in[1];
  const int*   et    = (const int*)d_in[2];
  const float* W1    = (const float*)d_in[3];
  const float* root1 = (const float*)d_in[4];
  const float* b1    = (const float*)d_in[5];
  const float* W2    = (const float*)d_in[6];
  const float* root2 = (const float*)d_in[7];
  const float* b2    = (const float*)d_in[8];
  float* out = (float*)d_out;

  const int E = in_sizes[2];
  const int* src  = ei;
  const int* dstv = ei + E;

  // workspace layout (~135 MB, 16B-aligned blocks)
  char* ws = (char*)d_ws;
  unsigned short* xb  = (unsigned short*)ws;                 // 12,812,288 B
  unsigned short* hb  = (unsigned short*)(ws + 12812288);    // 12,812,288 B
  unsigned short* agg = (unsigned short*)(ws + 25624576);    // 102,498,304 B
  unsigned short* Wt1 = (unsigned short*)(ws + 128122880);   //    294,912 B
  unsigned short* Wt2 = (unsigned short*)(ws + 128417792);   //    147,456 B
  int* cnt     = (int*)(ws + 128565248);                     // PADSEG*4 = 1,605,632 B
  int* fillpos = (int*)(ws + 130170880);                     // PADSEG*4 = 1,605,632 B
  int* blkSum  = (int*)(ws + 131776512);                     //      1,024 B
  int* srt     = (int*)(ws + 131777536);                     //  3,200,000 B

  // build segment structure: count (+x convert) -> scan -> fill
  hipMemsetAsync(cnt, 0, sizeof(int) * (size_t)PADSEG, stream);
  convert_count<<<PADN * 16 / 256, 256, 0, stream>>>(x, (unsigned*)xb, dstv, et, E, cnt);
  scan_block<<<NBLK, 256, 0, stream>>>(cnt, fillpos, blkSum);
  scan_tops<<<1, 256, 0, stream>>>(blkSum);
  scan_apply<<<NBLK, 256, 0, stream>>>(fillpos, blkSum);
  fill_edges<<<(E + 255) / 256, 256, 0, stream>>>(src, dstv, et, E, fillpos, srt);
  // after fill: fillpos[s] = segment end

  prep_w<<<(9 * 128 * KD + 9 * 64 * KD) / 256, 256, 0, stream>>>(W1, root1, W2, root2, Wt1, Wt2);

  const int gatherBlocks = NSEG / 16;   // 25000
  const int mBlocks = PADN / 128;       // 391

  // layer 1
  gather_mean<<<gatherBlocks, 256, 0, stream>>>((const unsigned*)xb, srt, fillpos, cnt, (unsigned*)agg);
  rgcn_gemm_mfma<128, true, true><<<mBlocks, 256, 0, stream>>>(agg, xb, Wt1, b1, hb);

  // layer 2
  gather_mean<<<gatherBlocks, 256, 0, stream>>>((const unsigned*)hb, srt, fillpos, cnt, (unsigned*)agg);
  rgcn_gemm_mfma<64, false, false><<<mBlocks, 256, 0, stream>>>(agg, hb, Wt2, b2, out);
}

// Round 7
// 221.371 us; speedup vs baseline: 1.8870x; 1.1622x over previous
//
#include <hip/hip_runtime.h>

constexpr int NN   = 50000;
constexpr int PADN = 50048;       // 391*128, padded rows
constexpr int KD   = 128;
constexpr int RR   = 8;
constexpr int NSEG = RR * NN;     // 400000
constexpr int NBLK = 196;         // scan blocks: 196*2048 = 401408 >= NSEG
constexpr int PADSEG = NBLK * 2048;

typedef __attribute__((ext_vector_type(8))) short short8;
typedef __attribute__((ext_vector_type(4))) float f32x4;
typedef __attribute__((ext_vector_type(4))) unsigned int u32x4;

__device__ __forceinline__ float bflo(unsigned u){ return __uint_as_float(u << 16); }
__device__ __forceinline__ float bfhi(unsigned u){ return __uint_as_float(u & 0xffff0000u); }
__device__ __forceinline__ unsigned pk_bf16(float a, float b){
  unsigned ua = __float_as_uint(a), ub = __float_as_uint(b);
  ua = (ua + 0x7fffu + ((ua >> 16) & 1u)) >> 16;
  ub = (ub + 0x7fffu + ((ub >> 16) & 1u)) & 0xffff0000u;
  return (ua & 0xffffu) | ub;
}
__device__ __forceinline__ unsigned short bf1(float a){
  unsigned ua = __float_as_uint(a);
  return (unsigned short)((ua + 0x7fffu + ((ua >> 16) & 1u)) >> 16);
}

// ---------------- pass 1: convert x to bf16 + rank-assign (single atomic pass) ----
// After this kernel, cnt[seg] == per-segment edge count AND rank[e] is e's
// unique slot within its segment.
__global__ __launch_bounds__(256)
void convert_count_rank(const float* __restrict__ x, unsigned* __restrict__ xb,
                        const int* __restrict__ dst, const int* __restrict__ et,
                        int E, int* __restrict__ cnt, int* __restrict__ rank) {
  const int idx = blockIdx.x * 256 + threadIdx.x;
  if (idx < E) rank[idx] = atomicAdd(&cnt[et[idx] * NN + dst[idx]], 1);
  if (idx < PADN * 16) {
    const int row = idx >> 4, o = (idx & 15) * 8;
    uint4 v = make_uint4(0u, 0u, 0u, 0u);
    if (row < NN) {
      float4 a = *(const float4*)&x[(size_t)row * KD + o];
      float4 b = *(const float4*)&x[(size_t)row * KD + o + 4];
      v.x = pk_bf16(a.x, a.y); v.y = pk_bf16(a.z, a.w);
      v.z = pk_bf16(b.x, b.y); v.w = pk_bf16(b.z, b.w);
    }
    *(uint4*)&xb[(size_t)idx * 4] = v;
  }
}

// hierarchical exclusive scan, stage 1: per-block (2048 segs) scan, no atomics
__global__ __launch_bounds__(256)
void scan_block(const int* __restrict__ cnt, int* __restrict__ fillpos,
                int* __restrict__ blkSum) {
  const int t = threadIdx.x;
  const int base = blockIdx.x * 2048 + t * 8;
  const int4 a = *(const int4*)&cnt[base];
  const int4 b = *(const int4*)&cnt[base + 4];
  const int s8[8] = {a.x, a.y, a.z, a.w, b.x, b.y, b.z, b.w};
  int tsum = 0;
#pragma unroll
  for (int i = 0; i < 8; ++i) tsum += s8[i];
  int inc = tsum;
#pragma unroll
  for (int o = 1; o < 64; o <<= 1) {
    int v = __shfl_up(inc, o);
    if ((t & 63) >= o) inc += v;
  }
  __shared__ int wsum[4];
  if ((t & 63) == 63) wsum[t >> 6] = inc;
  __syncthreads();
  int wpre = 0;
#pragma unroll
  for (int w = 0; w < 4; ++w) if (w < (t >> 6)) wpre += wsum[w];
  int run = wpre + inc - tsum;
  int o8[8];
#pragma unroll
  for (int i = 0; i < 8; ++i) { o8[i] = run; run += s8[i]; }
  *(int4*)&fillpos[base]     = make_int4(o8[0], o8[1], o8[2], o8[3]);
  *(int4*)&fillpos[base + 4] = make_int4(o8[4], o8[5], o8[6], o8[7]);
  if (t == 255) blkSum[blockIdx.x] = wpre + inc;
}

__global__ __launch_bounds__(256)
void scan_tops(int* __restrict__ blkSum) {
  const int t = threadIdx.x;
  const int v = (t < NBLK) ? blkSum[t] : 0;
  int inc = v;
#pragma unroll
  for (int o = 1; o < 64; o <<= 1) {
    int u = __shfl_up(inc, o);
    if ((t & 63) >= o) inc += u;
  }
  __shared__ int wsum[4];
  if ((t & 63) == 63) wsum[t >> 6] = inc;
  __syncthreads();
  int wpre = 0;
#pragma unroll
  for (int w = 0; w < 4; ++w) if (w < (t >> 6)) wpre += wsum[w];
  if (t < NBLK) blkSum[t] = wpre + inc - v;
}

__global__ __launch_bounds__(256)
void scan_apply(int* __restrict__ fillpos, const int* __restrict__ blkSum) {
  const int base = blockIdx.x * 2048 + threadIdx.x * 8;
  const int off = blkSum[blockIdx.x];
  int4 a = *(int4*)&fillpos[base];
  int4 b = *(int4*)&fillpos[base + 4];
  a.x += off; a.y += off; a.z += off; a.w += off;
  b.x += off; b.y += off; b.z += off; b.w += off;
  *(int4*)&fillpos[base]     = a;
  *(int4*)&fillpos[base + 4] = b;
}

// ---------------- pass 2: scatter srcs to sorted order, NO atomics ----------------
__global__ __launch_bounds__(256)
void fill_scatter(const int* __restrict__ src, const int* __restrict__ dst,
                  const int* __restrict__ et, const int* __restrict__ rank,
                  int E, const int* __restrict__ segbase, int* __restrict__ srt) {
  const int e = blockIdx.x * 256 + threadIdx.x;
  if (e < E) {
    const int seg = et[e] * NN + dst[e];
    srt[segbase[seg] + rank[e]] = src[e];
  }
}

// Wt1[9][128][128] and Wt2[9][64][128] bf16, transposed, in one dispatch
__global__ __launch_bounds__(256)
void prep_w(const float* __restrict__ W1, const float* __restrict__ root1,
            const float* __restrict__ W2, const float* __restrict__ root2,
            unsigned short* __restrict__ Wt1, unsigned short* __restrict__ Wt2) {
  int idx = blockIdx.x * 256 + threadIdx.x;
  if (idx < 9 * 128 * KD) {
    const int k = idx & 127;
    const int n = (idx >> 7) & 127;
    const int ch = idx >> 14;
    const float v = (ch < 8) ? W1[((size_t)ch * KD + k) * 128 + n] : root1[(size_t)k * 128 + n];
    Wt1[idx] = bf1(v);
  } else {
    idx -= 9 * 128 * KD;
    const int k = idx & 127;
    const int n = (idx >> 7) & 63;
    const int ch = idx >> 13;
    const float v = (ch < 8) ? W2[((size_t)ch * KD + k) * 64 + n] : root2[(size_t)k * 64 + n];
    Wt2[idx] = bf1(v);
  }
}

// ---------------- gather: agg[r][d][:] = mean of bf16 X rows ----------------
// 16 lanes per segment; NT store so the 100MB agg stream doesn't thrash L3
__global__ __launch_bounds__(256)
void gather_mean(const unsigned* __restrict__ Xb,         // [PADN][64] uint
                 const int* __restrict__ srt,
                 const int* __restrict__ segbase, const int* __restrict__ cnt,
                 unsigned* __restrict__ agg) {            // [8][PADN][64] uint
  const int g = blockIdx.x * 16 + (threadIdx.x >> 4);
  const int lane = threadIdx.x & 15;
  const int c = cnt[g];
  const int base = segbase[g];
  float acc[8] = {};
  int i = 0;
  for (; i + 1 < c; i += 2) {
    const int s0 = srt[base + i], s1 = srt[base + i + 1];
    const uint4 v0 = *(const uint4*)&Xb[(size_t)s0 * 64 + lane * 4];
    const uint4 v1 = *(const uint4*)&Xb[(size_t)s1 * 64 + lane * 4];
    acc[0] += bflo(v0.x) + bflo(v1.x); acc[1] += bfhi(v0.x) + bfhi(v1.x);
    acc[2] += bflo(v0.y) + bflo(v1.y); acc[3] += bfhi(v0.y) + bfhi(v1.y);
    acc[4] += bflo(v0.z) + bflo(v1.z); acc[5] += bfhi(v0.z) + bfhi(v1.z);
    acc[6] += bflo(v0.w) + bflo(v1.w); acc[7] += bfhi(v0.w) + bfhi(v1.w);
  }
  if (i < c) {
    const uint4 v0 = *(const uint4*)&Xb[(size_t)srt[base + i] * 64 + lane * 4];
    acc[0] += bflo(v0.x); acc[1] += bfhi(v0.x);
    acc[2] += bflo(v0.y); acc[3] += bfhi(v0.y);
    acc[4] += bflo(v0.z); acc[5] += bfhi(v0.z);
    acc[6] += bflo(v0.w); acc[7] += bfhi(v0.w);
  }
  const float sc = (c > 0) ? 1.0f / (float)c : 0.0f;
  u32x4 o;
  o.x = pk_bf16(acc[0] * sc, acc[1] * sc); o.y = pk_bf16(acc[2] * sc, acc[3] * sc);
  o.z = pk_bf16(acc[4] * sc, acc[5] * sc); o.w = pk_bf16(acc[6] * sc, acc[7] * sc);
  const int r = g / NN, d = g - r * NN;
  __builtin_nontemporal_store(o, (u32x4*)&agg[((size_t)r * PADN + d) * 64 + lane * 4]);
}

// ---------------- MFMA GEMM ----------------
// C[M,BN] = sum_{ch<8} agg_ch[M,128] @ Wt_ch^T + xrow[M,128] @ Wt_8^T (+bias)(relu)
// BM=128, BK=64, 256 threads = 4 waves. LDS XOR-swizzled. A loads non-temporal.
template<int BN, bool RELU, bool OUTBF16>
__global__ __launch_bounds__(256)
void rgcn_gemm_mfma(const unsigned short* __restrict__ agg,   // [8][PADN][128] bf16
                    const unsigned short* __restrict__ xrow,  // [PADN][128] bf16
                    const unsigned short* __restrict__ Wt,    // [9][BN][128] bf16
                    const float* __restrict__ bias,
                    void* __restrict__ Cout) {
  constexpr int WM = (BN == 128) ? 64 : 32;
  constexpr int MF = WM / 16;
  constexpr int NF = 4;
  constexpr int WAVES_N = BN / 64;

  __shared__ uint4 ldsv[(128 * 128 + BN * 128) / 16];
  char* As = (char*)ldsv;                 // [128][128B] swizzled
  char* Bs = (char*)ldsv + 128 * 128;     // [BN][128B]  swizzled

  const int t = threadIdx.x;
  const int l = t & 63;
  const int w = t >> 6;
  const int wr = w / WAVES_N;
  const int wc = w % WAVES_N;
  const int row0 = blockIdx.x * 128;
  const int l15 = l & 15, lq = l >> 4;

  f32x4 acc[MF][NF];
#pragma unroll
  for (int mi = 0; mi < MF; ++mi)
#pragma unroll
    for (int ni = 0; ni < NF; ++ni) acc[mi][ni] = (f32x4){0.f, 0.f, 0.f, 0.f};

  for (int ch = 0; ch < 9; ++ch) {
    const unsigned short* aP = (ch < 8) ? (agg + (size_t)ch * PADN * KD) : xrow;
    const unsigned short* bP = Wt + (size_t)ch * BN * KD;
#pragma unroll
    for (int kt = 0; kt < 2; ++kt) {
      __syncthreads();
      // stage A: 128 rows x 64 bf16 (NT loads — streamed once)
#pragma unroll
      for (int i = 0; i < 4; ++i) {
        const int s = t + i * 256;
        const int r = s >> 3, c16 = s & 7;
        u32x4 v = __builtin_nontemporal_load(
            (const u32x4*)(aP + (size_t)(row0 + r) * KD + kt * 64 + c16 * 8));
        *(u32x4*)(As + r * 128 + ((c16 ^ (r & 7)) * 16)) = v;
      }
      // stage B: BN rows x 64 bf16
#pragma unroll
      for (int i = 0; i < BN / 32; ++i) {
        const int s = t + i * 256;
        const int r = s >> 3, c16 = s & 7;
        uint4 v = *(const uint4*)(bP + (size_t)r * KD + kt * 64 + c16 * 8);
        *(uint4*)(Bs + r * 128 + ((c16 ^ (r & 7)) * 16)) = v;
      }
      __syncthreads();
#pragma unroll
      for (int ks = 0; ks < 2; ++ks) {
        short8 bfr[NF];
#pragma unroll
        for (int ni = 0; ni < NF; ++ni) {
          const int br = wc * 64 + ni * 16 + l15;
          bfr[ni] = *(const short8*)(Bs + br * 128 + (((ks * 4 + lq) ^ (br & 7)) * 16));
        }
#pragma unroll
        for (int mi = 0; mi < MF; ++mi) {
          const int ar = wr * WM + mi * 16 + l15;
          short8 af = *(const short8*)(As + ar * 128 + (((ks * 4 + lq) ^ (ar & 7)) * 16));
#pragma unroll
          for (int ni = 0; ni < NF; ++ni)
            acc[mi][ni] = __builtin_amdgcn_mfma_f32_16x16x32_bf16(af, bfr[ni], acc[mi][ni], 0, 0, 0);
        }
      }
    }
  }
  // epilogue
#pragma unroll
  for (int ni = 0; ni < NF; ++ni) {
    const int col = wc * 64 + ni * 16 + l15;
    const float bv = bias[col];
#pragma unroll
    for (int mi = 0; mi < MF; ++mi) {
#pragma unroll
      for (int q = 0; q < 4; ++q) {
        const int grow = row0 + wr * WM + mi * 16 + lq * 4 + q;
        if (grow < NN) {
          float v = acc[mi][ni][q] + bv;
          if (RELU) v = fmaxf(v, 0.f);
          if (OUTBF16) ((unsigned short*)Cout)[(size_t)grow * BN + col] = bf1(v);
          else         ((float*)Cout)[(size_t)grow * BN + col] = v;
        } else if (OUTBF16) {
          ((unsigned short*)Cout)[(size_t)grow * BN + col] = 0;  // clean pad rows
        }
      }
    }
  }
}

// ---------------- launch ----------------
extern "C" void kernel_launch(void* const* d_in, const int* in_sizes, int n_in,
                              void* d_out, int out_size, void* d_ws, size_t ws_size,
                              hipStream_t stream) {
  const float* x     = (const float*)d_in[0];
  const int*   ei    = (const int*)d_in[1];
  const int*   et    = (const int*)d_in[2];
  const float* W1    = (const float*)d_in[3];
  const float* root1 = (const float*)d_in[4];
  const float* b1    = (const float*)d_in[5];
  const float* W2    = (const float*)d_in[6];
  const float* root2 = (const float*)d_in[7];
  const float* b2    = (const float*)d_in[8];
  float* out = (float*)d_out;

  const int E = in_sizes[2];
  const int* src  = ei;
  const int* dstv = ei + E;

  // workspace layout (~135 MB, 16B-aligned blocks)
  char* ws = (char*)d_ws;
  unsigned short* xb  = (unsigned short*)ws;                 // 12,812,288 B
  unsigned short* hb  = (unsigned short*)(ws + 12812288);    // 12,812,288 B
  unsigned short* agg = (unsigned short*)(ws + 25624576);    // 102,498,304 B
  unsigned short* Wt1 = (unsigned short*)(ws + 128122880);   //    294,912 B
  unsigned short* Wt2 = (unsigned short*)(ws + 128417792);   //    147,456 B
  int* cnt     = (int*)(ws + 128565248);                     // PADSEG*4 = 1,605,632 B
  int* fillpos = (int*)(ws + 130170880);                     // PADSEG*4 = 1,605,632 B
  int* blkSum  = (int*)(ws + 131776512);                     //      1,024 B
  int* srt     = (int*)(ws + 131777536);                     //  3,200,000 B
  // rank lives inside agg: fully consumed by fill_scatter before agg is written
  int* rank    = (int*)agg;                                  //  3,200,000 B (aliased)

  // build segment structure: rank-assign (+x convert) -> scan -> scatter
  hipMemsetAsync(cnt, 0, sizeof(int) * (size_t)PADSEG, stream);
  convert_count_rank<<<PADN * 16 / 256, 256, 0, stream>>>(x, (unsigned*)xb, dstv, et, E, cnt, rank);
  scan_block<<<NBLK, 256, 0, stream>>>(cnt, fillpos, blkSum);
  scan_tops<<<1, 256, 0, stream>>>(blkSum);
  scan_apply<<<NBLK, 256, 0, stream>>>(fillpos, blkSum);
  fill_scatter<<<(E + 255) / 256, 256, 0, stream>>>(src, dstv, et, rank, E, fillpos, srt);
  // fillpos[s] = segment exclusive base (immutable from here on)

  prep_w<<<(9 * 128 * KD + 9 * 64 * KD) / 256, 256, 0, stream>>>(W1, root1, W2, root2, Wt1, Wt2);

  const int gatherBlocks = NSEG / 16;   // 25000
  const int mBlocks = PADN / 128;       // 391

  // layer 1
  gather_mean<<<gatherBlocks, 256, 0, stream>>>((const unsigned*)xb, srt, fillpos, cnt, (unsigned*)agg);
  rgcn_gemm_mfma<128, true, true><<<mBlocks, 256, 0, stream>>>(agg, xb, Wt1, b1, hb);

  // layer 2
  gather_mean<<<gatherBlocks, 256, 0, stream>>>((const unsigned*)hb, srt, fillpos, cnt, (unsigned*)agg);
  rgcn_gemm_mfma<64, false, false><<<mBlocks, 256, 0, stream>>>(agg, hb, Wt2, b2, out);
}